// Round 1
// baseline (216.097 us; speedup 1.0000x reference)
//
#include <hip/hip_runtime.h>

typedef __attribute__((ext_vector_type(8))) short bf16x8;
typedef __attribute__((ext_vector_type(4))) float f32x4;
typedef __attribute__((ext_vector_type(4))) unsigned short u16x4;
typedef unsigned short u16;
typedef unsigned int u32;

static __device__ __forceinline__ u16 f2bf(float f) {
  u32 u = __float_as_uint(f);
  u32 r = (u + 0x7fffu + ((u >> 16) & 1u)) >> 16;  // RNE
  return (u16)r;
}

#define GLDS16(g, l)                                                        \
  __builtin_amdgcn_global_load_lds(                                         \
      (const __attribute__((address_space(1))) u32*)(g),                    \
      (__attribute__((address_space(3))) u32*)(l), 16, 0, 0)

// ---------------- cast kernels ----------------
__global__ __launch_bounds__(256) void cast_x(const float* __restrict__ x,
                                              u16* __restrict__ xb) {
  int i = blockIdx.x * 256 + threadIdx.x;  // one thread per 8 elems
  const float4* xv = (const float4*)x;
  float4 a = xv[i * 2], b = xv[i * 2 + 1];
  bf16x8 o;
  o[0] = f2bf(a.x); o[1] = f2bf(a.y); o[2] = f2bf(a.z); o[3] = f2bf(a.w);
  o[4] = f2bf(b.x); o[5] = f2bf(b.y); o[6] = f2bf(b.z); o[7] = f2bf(b.w);
  *(bf16x8*)(xb + i * 8) = o;
}

// Wqkv_t[n][d], n = sel*1024 + h*64 + kk; value = W_sel[h][d][kk]
__global__ __launch_bounds__(256) void cast_wqkv(const float* __restrict__ wq,
                                                 const float* __restrict__ wk,
                                                 const float* __restrict__ wv,
                                                 u16* __restrict__ wt) {
  int tid = blockIdx.x * 256 + threadIdx.x;  // 3M
  int n = tid >> 10, d = tid & 1023;
  int sel = n >> 10, r = n & 1023, h = r >> 6, kk = r & 63;
  const float* src = sel == 0 ? wq : (sel == 1 ? wk : wv);
  wt[tid] = f2bf(src[h * 65536 + d * 64 + kk]);
}

// WOt[n][k] = W_O[k][n]
__global__ __launch_bounds__(256) void cast_wo(const float* __restrict__ wo,
                                               u16* __restrict__ wt) {
  int tid = blockIdx.x * 256 + threadIdx.x;  // 1M
  int n = tid >> 10, k = tid & 1023;
  wt[tid] = f2bf(wo[k * 1024 + n]);
}

// ---------------- GEMM: C = A(bf16)[M,K] * Bt(bf16)[N,K]^T ----------------
// MODE 1: float C [M,N].  MODE 2: cols<2048 -> bf16 qk[M,2048]; cols>=2048 ->
//          Vt[(b*1024 + (col-2048))*2048 + s] with row = b*2048+s.
template <int MODE>
__global__ __launch_bounds__(256) void gemm_bt(const u16* __restrict__ A,
                                               const u16* __restrict__ Bt,
                                               void* __restrict__ Cp,
                                               u16* __restrict__ Vt, int M,
                                               int N, int K) {
  const int t = threadIdx.x;
  const int lane = t & 63, w = t >> 6;
  const int lr = lane & 15, lg = lane >> 4;
  const int wr = w >> 1, wc = w & 1;
  const int m0 = blockIdx.y * 128, n0 = blockIdx.x * 128;
  __shared__ __align__(16) u16 As[128 * 32];
  __shared__ __align__(16) u16 Bs[128 * 32];
  f32x4 acc[4][4] = {};
  for (int k0 = 0; k0 < K; k0 += 32) {
#pragma unroll
    for (int j = 0; j < 2; ++j) {
      int idx = j * 256 + t;
      int row = idx >> 2, cb = (idx & 3) * 8;
      GLDS16(A + (size_t)(m0 + row) * K + k0 + cb, &As[idx * 8]);
      GLDS16(Bt + (size_t)(n0 + row) * K + k0 + cb, &Bs[idx * 8]);
    }
    __syncthreads();
    bf16x8 a[4], b[4];
#pragma unroll
    for (int m = 0; m < 4; ++m)
      a[m] = *(const bf16x8*)&As[(wr * 64 + m * 16 + lr) * 32 + lg * 8];
#pragma unroll
    for (int n = 0; n < 4; ++n)
      b[n] = *(const bf16x8*)&Bs[(wc * 64 + n * 16 + lr) * 32 + lg * 8];
#pragma unroll
    for (int m = 0; m < 4; ++m)
#pragma unroll
      for (int n = 0; n < 4; ++n)
        acc[m][n] =
            __builtin_amdgcn_mfma_f32_16x16x32_bf16(a[m], b[n], acc[m][n], 0, 0, 0);
    __syncthreads();
  }
#pragma unroll
  for (int m = 0; m < 4; ++m) {
    int rowg = m0 + wr * 64 + m * 16 + lg * 4;
#pragma unroll
    for (int n = 0; n < 4; ++n) {
      int colg = n0 + wc * 64 + n * 16 + lr;
      if (MODE == 1) {
        float* C = (float*)Cp;
#pragma unroll
        for (int j = 0; j < 4; ++j)
          C[(size_t)(rowg + j) * N + colg] = acc[m][n][j];
      } else {
        if (colg < 2048) {
          u16* C = (u16*)Cp;
#pragma unroll
          for (int j = 0; j < 4; ++j)
            C[(size_t)(rowg + j) * 2048 + colg] = f2bf(acc[m][n][j]);
        } else {
          int vidx = colg - 2048, bb = rowg >> 11, s = rowg & 2047;
          u16x4 pk;
#pragma unroll
          for (int j = 0; j < 4; ++j) pk[j] = f2bf(acc[m][n][j]);
          *(u16x4*)(Vt + (size_t)(bb * 1024 + vidx) * 2048 + s) = pk;
        }
      }
    }
  }
}

// ---------------- flash attention ----------------
// grid: 1024 blocks = (b,h) * 32 q-tiles of 64 rows; 4 waves * 16 q-rows.
__global__ __launch_bounds__(256) void attn(const u16* __restrict__ qkb,
                                            const u16* __restrict__ vtb,
                                            u16* __restrict__ hb) {
  const int t = threadIdx.x, lane = t & 63, w = t >> 6;
  const int lr = lane & 15, lg = lane >> 4;
  int blk = blockIdx.x;
  int qi = blk & 31, bh = blk >> 5;
  int b = bh >> 4, h = bh & 15;
  int q0 = qi * 64;
  __shared__ __align__(16) u16 Ks[64 * 64];   // [s][dk], blk^=(s&7) swizzle
  __shared__ __align__(16) u16 Vts[64 * 64];  // [dk][s], blk^=(d&7) swizzle
  __shared__ __align__(16) u16 Ps[4 * 16 * 72];  // per-wave P, rows padded to 72
  const float SC2 = 0.125f * 1.44269504088896340736f;  // scale * log2(e)

  const u16* qbase = qkb + (size_t)(b * 2048 + q0 + w * 16 + lr) * 2048 + h * 64;
  bf16x8 qf0 = *(const bf16x8*)(qbase + lg * 8);
  bf16x8 qf1 = *(const bf16x8*)(qbase + 32 + lg * 8);

  f32x4 oacc[4] = {};
  float mrun[4], lrun[4];
#pragma unroll
  for (int j = 0; j < 4; ++j) { mrun[j] = -1e30f; lrun[j] = 0.f; }

  const u16* Kg = qkb + (size_t)(b * 2048) * 2048 + 1024 + h * 64;
  const u16* Vg = vtb + (size_t)(b * 1024 + h * 64) * 2048;
  u16* Pw = &Ps[w * 16 * 72];

  for (int kv0 = 0; kv0 < 2048; kv0 += 64) {
#pragma unroll
    for (int j2 = 0; j2 < 2; ++j2) {
      int idx = j2 * 256 + t;
      int rr = idx >> 3, cb = idx & 7;
      GLDS16(Kg + (size_t)(kv0 + rr) * 2048 + (size_t)((cb ^ (rr & 7)) * 8),
             &Ks[idx * 8]);
      GLDS16(Vg + (size_t)rr * 2048 + kv0 + (size_t)((cb ^ (rr & 7)) * 8),
             &Vts[idx * 8]);
    }
    __syncthreads();

    f32x4 sacc[4] = {};
#pragma unroll
    for (int kk = 0; kk < 2; ++kk) {
      bf16x8 qf = kk ? qf1 : qf0;
#pragma unroll
      for (int n = 0; n < 4; ++n) {
        int s = n * 16 + lr;
        bf16x8 kf =
            *(const bf16x8*)&Ks[s * 64 + (((kk * 4 + lg) ^ (s & 7)) * 8)];
        sacc[n] = __builtin_amdgcn_mfma_f32_16x16x32_bf16(qf, kf, sacc[n], 0, 0, 0);
      }
    }

    // online softmax (exp2 domain), rows r = 4*lg + j per wave
    float pm[4];
#pragma unroll
    for (int j = 0; j < 4; ++j) {
      float v0 = fmaxf(sacc[0][j], sacc[1][j]);
      float v1 = fmaxf(sacc[2][j], sacc[3][j]);
      pm[j] = fmaxf(v0, v1) * SC2;
    }
#pragma unroll
    for (int mk = 1; mk <= 8; mk <<= 1)
#pragma unroll
      for (int j = 0; j < 4; ++j) pm[j] = fmaxf(pm[j], __shfl_xor(pm[j], mk));
    float mnew[4], al[4], psum[4];
#pragma unroll
    for (int j = 0; j < 4; ++j) {
      mnew[j] = fmaxf(mrun[j], pm[j]);
      al[j] = exp2f(mrun[j] - mnew[j]);
      psum[j] = 0.f;
    }
#pragma unroll
    for (int n = 0; n < 4; ++n)
#pragma unroll
      for (int j = 0; j < 4; ++j) {
        float p = exp2f(sacc[n][j] * SC2 - mnew[j]);
        psum[j] += p;
        Pw[(lg * 4 + j) * 72 + n * 16 + lr] = f2bf(p);
      }
#pragma unroll
    for (int mk = 1; mk <= 8; mk <<= 1)
#pragma unroll
      for (int j = 0; j < 4; ++j) psum[j] += __shfl_xor(psum[j], mk);
#pragma unroll
    for (int j = 0; j < 4; ++j) {
      lrun[j] = lrun[j] * al[j] + psum[j];
      mrun[j] = mnew[j];
    }
#pragma unroll
    for (int n = 0; n < 4; ++n)
#pragma unroll
      for (int j = 0; j < 4; ++j) oacc[n][j] *= al[j];

    // PV: A-frag from own P rows, B-frag from swizzled Vt
#pragma unroll
    for (int kk = 0; kk < 2; ++kk) {
      bf16x8 pf = *(const bf16x8*)&Pw[lr * 72 + kk * 32 + lg * 8];
#pragma unroll
      for (int n = 0; n < 4; ++n) {
        int d = n * 16 + lr;
        bf16x8 vf =
            *(const bf16x8*)&Vts[d * 64 + (((kk * 4 + lg) ^ (d & 7)) * 8)];
        oacc[n] = __builtin_amdgcn_mfma_f32_16x16x32_bf16(pf, vf, oacc[n], 0, 0, 0);
      }
    }
    __syncthreads();
  }

  int rowg = b * 2048 + q0 + w * 16 + lg * 4;
#pragma unroll
  for (int n = 0; n < 4; ++n) {
    int col = h * 64 + n * 16 + lr;
#pragma unroll
    for (int j = 0; j < 4; ++j)
      hb[(size_t)(rowg + j) * 1024 + col] = f2bf(oacc[n][j] / lrun[j]);
  }
}

extern "C" void kernel_launch(void* const* d_in, const int* in_sizes, int n_in,
                              void* d_out, int out_size, void* d_ws,
                              size_t ws_size, hipStream_t stream) {
  const float* x = (const float*)d_in[0];
  const float* wq = (const float*)d_in[1];
  const float* wk = (const float*)d_in[2];
  const float* wv = (const float*)d_in[3];
  const float* wo = (const float*)d_in[4];

  u16* xb = (u16*)d_ws;              // [4096][1024]        4M
  u16* wqkv = xb + 4 * 1024 * 1024;  // [3072][1024]        3M
  u16* wot = wqkv + 3 * 1024 * 1024; // [1024][1024]        1M
  u16* qkb = wot + 1024 * 1024;      // [4096][2048] Q|K    8M
  u16* vtb = qkb + 8 * 1024 * 1024;  // [2][1024][2048] Vt  4M
  u16* hb = vtb + 4 * 1024 * 1024;   // [4096][1024] heads  4M

  cast_x<<<2048, 256, 0, stream>>>(x, xb);
  cast_wqkv<<<12288, 256, 0, stream>>>(wq, wk, wv, wqkv);
  cast_wo<<<4096, 256, 0, stream>>>(wo, wot);
  gemm_bt<2><<<dim3(24, 32), 256, 0, stream>>>(xb, wqkv, qkb, vtb, 4096, 3072, 1024);
  attn<<<1024, 256, 0, stream>>>(qkb, vtb, hb);
  gemm_bt<1><<<dim3(8, 32), 256, 0, stream>>>(hb, wot, d_out, nullptr, 4096, 1024, 1024);
}

// Round 2
// 162.967 us; speedup vs baseline: 1.3260x; 1.3260x over previous
//
#include <hip/hip_runtime.h>

typedef __attribute__((ext_vector_type(8))) short bf16x8;
typedef __attribute__((ext_vector_type(4))) float f32x4;
typedef __attribute__((ext_vector_type(4))) unsigned short u16x4;
typedef unsigned short u16;
typedef unsigned int u32;

static __device__ __forceinline__ u16 f2bf(float f) {
  u32 u = __float_as_uint(f);
  u32 r = (u + 0x7fffu + ((u >> 16) & 1u)) >> 16;  // RNE
  return (u16)r;
}

static __device__ __forceinline__ u32 cvt_pk(float lo, float hi) {
  u32 r;
  asm("v_cvt_pk_bf16_f32 %0, %1, %2" : "=v"(r) : "v"(lo), "v"(hi));
  return r;
}

#define GLDS16(g, l)                                                        \
  __builtin_amdgcn_global_load_lds(                                         \
      (const __attribute__((address_space(1))) u32*)(g),                    \
      (__attribute__((address_space(3))) u32*)(l), 16, 0, 0)

// ---------------- cast kernels ----------------
__global__ __launch_bounds__(256) void cast_x(const float* __restrict__ x,
                                              u16* __restrict__ xb) {
  int i = blockIdx.x * 256 + threadIdx.x;  // one thread per 8 elems
  const float4* xv = (const float4*)x;
  float4 a = xv[i * 2], b = xv[i * 2 + 1];
  bf16x8 o;
  o[0] = f2bf(a.x); o[1] = f2bf(a.y); o[2] = f2bf(a.z); o[3] = f2bf(a.w);
  o[4] = f2bf(b.x); o[5] = f2bf(b.y); o[6] = f2bf(b.z); o[7] = f2bf(b.w);
  *(bf16x8*)(xb + i * 8) = o;
}

// Wqkv_t[n][d], n = sel*1024 + h*64 + kk; value = W_sel[h][d][kk]
__global__ __launch_bounds__(256) void cast_wqkv(const float* __restrict__ wq,
                                                 const float* __restrict__ wk,
                                                 const float* __restrict__ wv,
                                                 u16* __restrict__ wt) {
  int tid = blockIdx.x * 256 + threadIdx.x;  // 3M
  int n = tid >> 10, d = tid & 1023;
  int sel = n >> 10, r = n & 1023, h = r >> 6, kk = r & 63;
  const float* src = sel == 0 ? wq : (sel == 1 ? wk : wv);
  wt[tid] = f2bf(src[h * 65536 + d * 64 + kk]);
}

// WOt[n][k] = W_O[k][n]
__global__ __launch_bounds__(256) void cast_wo(const float* __restrict__ wo,
                                               u16* __restrict__ wt) {
  int tid = blockIdx.x * 256 + threadIdx.x;  // 1M
  int n = tid >> 10, k = tid & 1023;
  wt[tid] = f2bf(wo[k * 1024 + n]);
}

// ---------------- GEMM: C = A(bf16)[M,K] * Bt(bf16)[N,K]^T ----------------
// MODE 1: float C [M,N].  MODE 2: cols<2048 -> bf16 qk[M,2048]; cols>=2048 ->
//          Vt[(b*1024 + (col-2048))*2048 + s] with row = b*2048+s.
template <int MODE>
__global__ __launch_bounds__(256) void gemm_bt(const u16* __restrict__ A,
                                               const u16* __restrict__ Bt,
                                               void* __restrict__ Cp,
                                               u16* __restrict__ Vt, int M,
                                               int N, int K) {
  const int t = threadIdx.x;
  const int lane = t & 63, w = t >> 6;
  const int lr = lane & 15, lg = lane >> 4;
  const int wr = w >> 1, wc = w & 1;
  const int m0 = blockIdx.y * 128, n0 = blockIdx.x * 128;
  __shared__ __align__(16) u16 As[128 * 32];
  __shared__ __align__(16) u16 Bs[128 * 32];
  f32x4 acc[4][4] = {};
  for (int k0 = 0; k0 < K; k0 += 32) {
#pragma unroll
    for (int j = 0; j < 2; ++j) {
      int idx = j * 256 + t;
      int row = idx >> 2, cb = (idx & 3) * 8;
      GLDS16(A + (size_t)(m0 + row) * K + k0 + cb, &As[idx * 8]);
      GLDS16(Bt + (size_t)(n0 + row) * K + k0 + cb, &Bs[idx * 8]);
    }
    __syncthreads();
    bf16x8 a[4], b[4];
#pragma unroll
    for (int m = 0; m < 4; ++m)
      a[m] = *(const bf16x8*)&As[(wr * 64 + m * 16 + lr) * 32 + lg * 8];
#pragma unroll
    for (int n = 0; n < 4; ++n)
      b[n] = *(const bf16x8*)&Bs[(wc * 64 + n * 16 + lr) * 32 + lg * 8];
#pragma unroll
    for (int m = 0; m < 4; ++m)
#pragma unroll
      for (int n = 0; n < 4; ++n)
        acc[m][n] =
            __builtin_amdgcn_mfma_f32_16x16x32_bf16(a[m], b[n], acc[m][n], 0, 0, 0);
    __syncthreads();
  }
#pragma unroll
  for (int m = 0; m < 4; ++m) {
    int rowg = m0 + wr * 64 + m * 16 + lg * 4;
#pragma unroll
    for (int n = 0; n < 4; ++n) {
      int colg = n0 + wc * 64 + n * 16 + lr;
      if (MODE == 1) {
        float* C = (float*)Cp;
#pragma unroll
        for (int j = 0; j < 4; ++j)
          C[(size_t)(rowg + j) * N + colg] = acc[m][n][j];
      } else {
        if (colg < 2048) {
          u16* C = (u16*)Cp;
#pragma unroll
          for (int j = 0; j < 4; ++j)
            C[(size_t)(rowg + j) * 2048 + colg] = f2bf(acc[m][n][j]);
        } else {
          int vidx = colg - 2048, bb = rowg >> 11, s = rowg & 2047;
          u16x4 pk;
#pragma unroll
          for (int j = 0; j < 4; ++j) pk[j] = f2bf(acc[m][n][j]);
          *(u16x4*)(Vt + (size_t)(bb * 1024 + vidx) * 2048 + s) = pk;
        }
      }
    }
  }
}

// ---------------- flash attention (swapped QK^T, in-register softmax) -----
// grid: 1024 blocks = (b,h) * 32 q-tiles of 64 rows; 4 waves * 16 q-rows.
// Swapped: sacc = mfma(K_frag, Q_frag) => lane holds S[q=lr][k=16n+4lg+j];
// softmax state (m,l) is a per-lane scalar for row q=lr.
__global__ __launch_bounds__(256) void attn(const u16* __restrict__ qkb,
                                            const u16* __restrict__ vtb,
                                            u16* __restrict__ hb) {
  const int t = threadIdx.x, lane = t & 63, w = t >> 6;
  const int lr = lane & 15, lg = lane >> 4;
  int blk = blockIdx.x;
  int qi = blk & 31, bh = blk >> 5;
  int b = bh >> 4, h = bh & 15;
  int q0 = qi * 64;
  __shared__ __align__(16) u16 Ks[64 * 64];   // [s][dk], chunk^=(s&7) swizzle
  __shared__ __align__(16) u16 Vts[64 * 64];  // [dk][s], chunk^=(d&7) swizzle
  __shared__ __align__(16) u32 Ps[4][16 * 36];  // per-wave P packed bf16 pairs
  const float SC2 = 0.125f * 1.44269504088896340736f;  // scale * log2(e)

  // Q fragment (B-operand): col=q=lr, k-slice = d
  const u16* qbase = qkb + (size_t)(b * 2048 + q0 + w * 16 + lr) * 2048 + h * 64;
  bf16x8 qf0 = *(const bf16x8*)(qbase + lg * 8);
  bf16x8 qf1 = *(const bf16x8*)(qbase + 32 + lg * 8);

  f32x4 oacc[4] = {};
  float mrun = -1e30f, lrun = 0.f;

  const u16* Kg = qkb + (size_t)(b * 2048) * 2048 + 1024 + h * 64;
  const u16* Vg = vtb + (size_t)(b * 1024 + h * 64) * 2048;
  u32* Pw = &Ps[w][0];

  for (int kv0 = 0; kv0 < 2048; kv0 += 64) {
#pragma unroll
    for (int j2 = 0; j2 < 2; ++j2) {
      int idx = j2 * 256 + t;
      int rr = idx >> 3, cb = idx & 7;
      GLDS16(Kg + (size_t)(kv0 + rr) * 2048 + (size_t)((cb ^ (rr & 7)) * 8),
             &Ks[idx * 8]);
      GLDS16(Vg + (size_t)rr * 2048 + kv0 + (size_t)((cb ^ (rr & 7)) * 8),
             &Vts[idx * 8]);
    }
    __syncthreads();

    // S^T = K * Q^T : lane holds S[q=lr][k = 16n + 4lg + j]
    f32x4 sacc[4] = {};
    __builtin_amdgcn_s_setprio(1);
#pragma unroll
    for (int kk = 0; kk < 2; ++kk) {
      bf16x8 qf = kk ? qf1 : qf0;
#pragma unroll
      for (int n = 0; n < 4; ++n) {
        int s = n * 16 + lr;
        bf16x8 kf =
            *(const bf16x8*)&Ks[s * 64 + (((kk * 4 + lg) ^ (s & 7)) * 8)];
        sacc[n] = __builtin_amdgcn_mfma_f32_16x16x32_bf16(kf, qf, sacc[n], 0, 0, 0);
      }
    }
    __builtin_amdgcn_s_setprio(0);

    // in-register online softmax (exp2 domain), per-lane scalar state
    float pm = sacc[0][0];
#pragma unroll
    for (int n = 0; n < 4; ++n)
#pragma unroll
      for (int j = 0; j < 4; ++j) pm = fmaxf(pm, sacc[n][j]);
    pm *= SC2;
    pm = fmaxf(pm, __shfl_xor(pm, 16));
    pm = fmaxf(pm, __shfl_xor(pm, 32));
    float mnew = fmaxf(mrun, pm);
    float al = __builtin_amdgcn_exp2f(mrun - mnew);
    float p[16];
    float ps = 0.f;
#pragma unroll
    for (int n = 0; n < 4; ++n)
#pragma unroll
      for (int j = 0; j < 4; ++j) {
        float v = __builtin_amdgcn_exp2f(sacc[n][j] * SC2 - mnew);
        p[n * 4 + j] = v;
        ps += v;
      }
    ps += __shfl_xor(ps, 16);
    ps += __shfl_xor(ps, 32);
    lrun = lrun * al + ps;
    mrun = mnew;

    // pack P: word idx = k/2 = 8n + 2lg + pp, row q = lr (pad 36 u32)
#pragma unroll
    for (int n = 0; n < 4; ++n)
#pragma unroll
      for (int pp = 0; pp < 2; ++pp)
        Pw[lr * 36 + 8 * n + 2 * lg + pp] =
            cvt_pk(p[n * 4 + 2 * pp], p[n * 4 + 2 * pp + 1]);

    // rescale O (oacc rows are q = 4lg + j; alpha lives in lane lr = q)
    float alj[4];
#pragma unroll
    for (int j = 0; j < 4; ++j) alj[j] = __shfl(al, 4 * lg + j);
#pragma unroll
    for (int n = 0; n < 4; ++n)
#pragma unroll
      for (int j = 0; j < 4; ++j) oacc[n][j] *= alj[j];

    // PV: A-frag = P[q=lr][k=32kk+8lg..+7] (4 u32, 16B aligned)
    __builtin_amdgcn_s_setprio(1);
#pragma unroll
    for (int kk = 0; kk < 2; ++kk) {
      bf16x8 pa = *(const bf16x8*)&Pw[lr * 36 + 16 * kk + 4 * lg];
#pragma unroll
      for (int n = 0; n < 4; ++n) {
        int d = n * 16 + lr;
        bf16x8 vf =
            *(const bf16x8*)&Vts[d * 64 + (((kk * 4 + lg) ^ (d & 7)) * 8)];
        oacc[n] = __builtin_amdgcn_mfma_f32_16x16x32_bf16(pa, vf, oacc[n], 0, 0, 0);
      }
    }
    __builtin_amdgcn_s_setprio(0);
    __syncthreads();
  }

  float rinv = __builtin_amdgcn_rcpf(lrun);
  float rj[4];
#pragma unroll
  for (int j = 0; j < 4; ++j) rj[j] = __shfl(rinv, 4 * lg + j);
  int rowg = b * 2048 + q0 + w * 16 + lg * 4;
#pragma unroll
  for (int n = 0; n < 4; ++n) {
    int col = h * 64 + n * 16 + lr;
#pragma unroll
    for (int j = 0; j < 4; ++j)
      hb[(size_t)(rowg + j) * 1024 + col] = f2bf(oacc[n][j] * rj[j]);
  }
}

extern "C" void kernel_launch(void* const* d_in, const int* in_sizes, int n_in,
                              void* d_out, int out_size, void* d_ws,
                              size_t ws_size, hipStream_t stream) {
  const float* x = (const float*)d_in[0];
  const float* wq = (const float*)d_in[1];
  const float* wk = (const float*)d_in[2];
  const float* wv = (const float*)d_in[3];
  const float* wo = (const float*)d_in[4];

  u16* xb = (u16*)d_ws;              // [4096][1024]        4M
  u16* wqkv = xb + 4 * 1024 * 1024;  // [3072][1024]        3M
  u16* wot = wqkv + 3 * 1024 * 1024; // [1024][1024]        1M
  u16* qkb = wot + 1024 * 1024;      // [4096][2048] Q|K    8M
  u16* vtb = qkb + 8 * 1024 * 1024;  // [2][1024][2048] Vt  4M
  u16* hb = vtb + 4 * 1024 * 1024;   // [4096][1024] heads  4M

  cast_x<<<2048, 256, 0, stream>>>(x, xb);
  cast_wqkv<<<12288, 256, 0, stream>>>(wq, wk, wv, wqkv);
  cast_wo<<<4096, 256, 0, stream>>>(wo, wot);
  gemm_bt<2><<<dim3(24, 32), 256, 0, stream>>>(xb, wqkv, qkb, vtb, 4096, 3072, 1024);
  attn<<<1024, 256, 0, stream>>>(qkb, vtb, hb);
  gemm_bt<1><<<dim3(8, 32), 256, 0, stream>>>(hb, wot, d_out, nullptr, 4096, 1024, 1024);
}